// Round 1
// baseline (736.344 us; speedup 1.0000x reference)
//
#include <hip/hip_runtime.h>
#include <hip/hip_fp16.h>

// Problem constants (fixed by the reference)
#define NN 50000      // nodes
#define EE 800000     // edges
#define FF 64         // F_IN = F_OUT
#define PP 8          // periods
#define NPAD 50048    // padded rows for ABuf (multiple of 64, >= max tile row)
#define KD 128        // GEMM K: 64 (X) + 64 (TX1)

typedef _Float16 half8 __attribute__((ext_vector_type(8)));
typedef float floatx4 __attribute__((ext_vector_type(4)));

static constexpr size_t al512(size_t x) { return (x + 511) & ~size_t(511); }
static constexpr size_t OFF_DEG  = 0;                               // float[NN]
static constexpr size_t OFF_CNT  = al512(OFF_DEG + (size_t)NN*4);   // int[NN]
static constexpr size_t OFF_DIS  = al512(OFF_CNT + (size_t)NN*4);   // float[NN]
static constexpr size_t OFF_ROWP = al512(OFF_DIS + (size_t)NN*4);   // int[NN+1]
static constexpr size_t OFF_CUR  = al512(OFF_ROWP + (size_t)(NN+1)*4); // int[NN]
static constexpr size_t OFF_CSRS = al512(OFF_CUR + (size_t)NN*4);   // int[EE]
static constexpr size_t OFF_CSRW = al512(OFF_CSRS + (size_t)EE*4);  // float[EE]
static constexpr size_t OFF_BIAS = al512(OFF_CSRW + (size_t)EE*4);  // float[192]
static constexpr size_t OFF_WC2  = al512(OFF_BIAS + 192*4);         // float[64]
static constexpr size_t OFF_WFRG = al512(OFF_WC2 + 64*4);           // half[4*12*64*8]
static constexpr size_t OFF_ABUF = al512(OFF_WFRG + (size_t)24576*2); // half[PP*NPAD*KD]

// ---- K1: out-degree by src (float) + in-degree count by dst (int) ----------
__global__ void k_deg_cnt(const int* __restrict__ src, const int* __restrict__ dst,
                          const float* __restrict__ ew,
                          float* __restrict__ deg, int* __restrict__ cnt) {
    int e = blockIdx.x * 256 + threadIdx.x;
    if (e < EE) {
        atomicAdd(deg + src[e], ew[e]);
        atomicAdd(cnt + dst[e], 1);
    }
}

// ---- K2: dis[n] = deg>0 ? rsqrt(max(deg,1e-12)) : 0 ------------------------
__global__ void k_dis(const float* __restrict__ deg, float* __restrict__ dis) {
    int n = blockIdx.x * 256 + threadIdx.x;
    if (n < NN) {
        float d = deg[n];
        dis[n] = d > 0.f ? rsqrtf(fmaxf(d, 1e-12f)) : 0.f;
    }
}

// ---- K3: single-block exclusive scan of cnt -> row_ptr, cursor -------------
__global__ void k_scan(const int* __restrict__ cnt, int* __restrict__ row_ptr,
                       int* __restrict__ cursor) {
    __shared__ int sm[1024];
    __shared__ int carry_s;
    int tid = threadIdx.x;
    if (tid == 0) carry_s = 0;
    __syncthreads();
    for (int base = 0; base < NN; base += 1024) {
        int i = base + tid;
        int v = (i < NN) ? cnt[i] : 0;
        sm[tid] = v;
        __syncthreads();
        for (int off = 1; off < 1024; off <<= 1) {  // inclusive Hillis-Steele
            int t = (tid >= off) ? sm[tid - off] : 0;
            __syncthreads();
            sm[tid] += t;
            __syncthreads();
        }
        int carry = carry_s;
        int excl = carry + sm[tid] - v;
        if (i < NN) { row_ptr[i] = excl; cursor[i] = excl; }
        __syncthreads();
        if (tid == 1023) carry_s = carry + sm[1023];
        __syncthreads();
    }
    if (tid == 0) row_ptr[NN] = carry_s;
}

// ---- K4: scatter edges into CSR buckets by dst -----------------------------
__global__ void k_scatter(const int* __restrict__ src, const int* __restrict__ dst,
                          const float* __restrict__ ew, const float* __restrict__ dis,
                          int* __restrict__ cursor, int* __restrict__ csr_src,
                          float* __restrict__ csr_wn) {
    int e = blockIdx.x * 256 + threadIdx.x;
    if (e < EE) {
        int s = src[e], d = dst[e];
        float wn = -dis[s] * ew[e] * dis[d];
        int pos = atomicAdd(cursor + d, 1);
        csr_src[pos] = s;
        csr_wn[pos] = wn;
    }
}

// ---- K5: transpose X (N,64,8) f32 -> ABuf[p][n][0..64) f16 -----------------
__global__ void k_xpose(const float* __restrict__ X, _Float16* __restrict__ ABuf) {
    int wid = threadIdx.x >> 6, lane = threadIdx.x & 63;
    int n = blockIdx.x * 4 + wid;
    if (n >= NN) return;
    const float4* xp = (const float4*)(X + (size_t)n * 512 + lane * 8);
    float4 a = xp[0], b = xp[1];
    float v[8] = {a.x, a.y, a.z, a.w, b.x, b.y, b.z, b.w};
#pragma unroll
    for (int p = 0; p < PP; ++p)
        ABuf[((size_t)p * NPAD + n) * KD + lane] = (_Float16)v[p];
}

// ---- K6: SpMM gather: TX1[p][n][f] = sum_e wn * X[src][f][p] ---------------
__global__ void k_spmm(const float* __restrict__ X, const int* __restrict__ row_ptr,
                       const int* __restrict__ csr_src, const float* __restrict__ csr_wn,
                       _Float16* __restrict__ ABuf) {
    int wid = threadIdx.x >> 6, lane = threadIdx.x & 63;
    int n = blockIdx.x * 4 + wid;
    if (n >= NN) return;
    float acc0 = 0.f, acc1 = 0.f, acc2 = 0.f, acc3 = 0.f;
    float acc4 = 0.f, acc5 = 0.f, acc6 = 0.f, acc7 = 0.f;
    int beg = row_ptr[n], end = row_ptr[n + 1];
    for (int k = beg; k < end; ++k) {
        int s = csr_src[k];
        float w = csr_wn[k];
        const float4* xp = (const float4*)(X + (size_t)s * 512 + lane * 8);
        float4 a = xp[0], b = xp[1];
        acc0 += w * a.x; acc1 += w * a.y; acc2 += w * a.z; acc3 += w * a.w;
        acc4 += w * b.x; acc5 += w * b.y; acc6 += w * b.z; acc7 += w * b.w;
    }
    float accs[8] = {acc0, acc1, acc2, acc3, acc4, acc5, acc6, acc7};
#pragma unroll
    for (int p = 0; p < PP; ++p)
        ABuf[((size_t)p * NPAD + n) * KD + 64 + lane] = (_Float16)accs[p];
}

// ---- K7: weight prep: pack W into MFMA B-fragment layout + biases ----------
// Wfrag[((ks*12+ct)*64 + lane)*8 + j] = W[k = ks*32 + (lane>>4)*8 + j][c = ct*16 + (lane&15)]
// where W[k][g'*64+j64] = (k<64 ? Wx0 : Wx1)[gmap[g']][k%64][j64]
__global__ void k_prep(const float* __restrict__ Wx0, const float* __restrict__ Wx1,
                       const float* __restrict__ bx, const float* __restrict__ bh,
                       const float* __restrict__ wc, const float* __restrict__ bg,
                       _Float16* __restrict__ Wfrag, float* __restrict__ biasv,
                       float* __restrict__ wc2) {
    int t = blockIdx.x * 256 + threadIdx.x;
    const int gmap[3] = {0, 2, 3};
    if (t < 24576) {
        int j8 = t & 7;
        int lane = (t >> 3) & 63;
        int rem = t >> 9;           // [0,48)
        int ct = rem % 12;
        int ks = rem / 12;
        int k = ks * 32 + (lane >> 4) * 8 + j8;
        int gp = ct >> 2;
        int g = gmap[gp];
        int j64 = (ct & 3) * 16 + (lane & 15);
        float val = (k < 64) ? Wx0[((size_t)g * 64 + k) * 64 + j64]
                             : Wx1[((size_t)g * 64 + (k - 64)) * 64 + j64];
        Wfrag[t] = (_Float16)val;
    }
    if (t < 192) {
        int gp = t / 64, j = t % 64;
        int g = gmap[gp];
        biasv[t] = bx[g * 64 + j] + bh[g * 64 + j] + bg[g * 64 + j];
    }
    if (t < 64) wc2[t] = wc[2 * 64 + t];
}

__device__ __forceinline__ float sigmoidf_fast(float x) {
    return 1.f / (1.f + __expf(-x));
}
__device__ __forceinline__ float tanhf_fast(float x) {
    float e2 = __expf(2.f * x);
    return 1.f - 2.f / (e2 + 1.f);
}

// ---- K8: MFMA GEMM (N x 128) @ (128 x 192) per period + fused LSTM epilogue
// Block = 256 thr = 4 waves; wave handles 16 nodes x 192 cols (12 MFMA tiles).
__global__ __launch_bounds__(256) void k_gemm(const _Float16* __restrict__ ABuf,
                                              const _Float16* __restrict__ Wfrag,
                                              const float* __restrict__ biasv,
                                              const float* __restrict__ wc2,
                                              float* __restrict__ out) {
    int wid = threadIdx.x >> 6, lane = threadIdx.x & 63;
    int n0 = blockIdx.x * 64 + wid * 16;
    int jj = lane & 15, quad = lane >> 4;

    float bi[4], bc[4], bo[4], wcv[4];
#pragma unroll
    for (int c4 = 0; c4 < 4; ++c4) {
        int j = c4 * 16 + jj;
        bi[c4] = biasv[j];
        bc[c4] = biasv[64 + j];
        bo[c4] = biasv[128 + j];
        wcv[c4] = wc2[j];
    }

    const half8* Wf = (const half8*)Wfrag;
    floatx4 outacc[4];
#pragma unroll
    for (int c4 = 0; c4 < 4; ++c4) outacc[c4] = (floatx4){0.f, 0.f, 0.f, 0.f};

    int arow = n0 + jj;  // A-fragment: m = lane&15

#pragma unroll 1
    for (int p = 0; p < PP; ++p) {
        const half8* Ap = (const half8*)(ABuf + ((size_t)p * NPAD + arow) * KD) + quad;
        floatx4 acc[12];
#pragma unroll
        for (int t = 0; t < 12; ++t) acc[t] = (floatx4){0.f, 0.f, 0.f, 0.f};
#pragma unroll
        for (int ks = 0; ks < 4; ++ks) {
            half8 af = Ap[ks * 4];  // k = ks*32 + quad*8 + j
#pragma unroll
            for (int ct = 0; ct < 12; ++ct) {
                half8 bf = Wf[(ks * 12 + ct) * 64 + lane];
                acc[ct] = __builtin_amdgcn_mfma_f32_16x16x32_f16(af, bf, acc[ct], 0, 0, 0);
            }
        }
        // fused epilogue: I=sig(ai); T=tanh(ac); Cn=I*T; O=sig(ao+wc2*Cn); out+=O*tanh(Cn)
#pragma unroll
        for (int c4 = 0; c4 < 4; ++c4) {
#pragma unroll
            for (int r = 0; r < 4; ++r) {
                float ai = acc[c4][r] + bi[c4];
                float ac = acc[4 + c4][r] + bc[c4];
                float ao = acc[8 + c4][r] + bo[c4];
                float I = sigmoidf_fast(ai);
                float T = tanhf_fast(ac);
                float Cn = I * T;
                float O = sigmoidf_fast(ao + wcv[c4] * Cn);
                outacc[c4][r] += O * tanhf_fast(Cn);
            }
        }
    }
    // store: row n = n0 + quad*4 + r, col = c4*16 + jj
#pragma unroll
    for (int c4 = 0; c4 < 4; ++c4) {
#pragma unroll
        for (int r = 0; r < 4; ++r) {
            int n = n0 + quad * 4 + r;
            if (n < NN) out[(size_t)n * 64 + c4 * 16 + jj] = outacc[c4][r];
        }
    }
}

extern "C" void kernel_launch(void* const* d_in, const int* in_sizes, int n_in,
                              void* d_out, int out_size, void* d_ws, size_t ws_size,
                              hipStream_t stream) {
    const float* X   = (const float*)d_in[0];
    const int*   ei  = (const int*)d_in[1];
    const float* ew  = (const float*)d_in[2];
    const float* Wx0 = (const float*)d_in[3];
    const float* Wx1 = (const float*)d_in[4];
    const float* bx  = (const float*)d_in[5];
    // d_in[6], d_in[7] (Wh0, Wh1) are dead: H=0
    const float* bh  = (const float*)d_in[8];
    const float* wc  = (const float*)d_in[9];
    const float* bg  = (const float*)d_in[10];
    float* out = (float*)d_out;

    const int* src = ei;
    const int* dst = ei + EE;

    char* ws = (char*)d_ws;
    float* deg     = (float*)(ws + OFF_DEG);
    int*   cnt     = (int*)(ws + OFF_CNT);
    float* dis     = (float*)(ws + OFF_DIS);
    int*   row_ptr = (int*)(ws + OFF_ROWP);
    int*   cursor  = (int*)(ws + OFF_CUR);
    int*   csr_src = (int*)(ws + OFF_CSRS);
    float* csr_wn  = (float*)(ws + OFF_CSRW);
    float* biasv   = (float*)(ws + OFF_BIAS);
    float* wc2     = (float*)(ws + OFF_WC2);
    _Float16* Wfrag = (_Float16*)(ws + OFF_WFRG);
    _Float16* ABuf  = (_Float16*)(ws + OFF_ABUF);

    // zero deg + cnt (contiguous region at front of ws)
    hipMemsetAsync(ws, 0, OFF_CNT + (size_t)NN * 4, stream);

    k_deg_cnt<<<(EE + 255) / 256, 256, 0, stream>>>(src, dst, ew, deg, cnt);
    k_dis<<<(NN + 255) / 256, 256, 0, stream>>>(deg, dis);
    k_scan<<<1, 1024, 0, stream>>>(cnt, row_ptr, cursor);
    k_scatter<<<(EE + 255) / 256, 256, 0, stream>>>(src, dst, ew, dis, cursor, csr_src, csr_wn);
    k_xpose<<<(NN + 3) / 4, 256, 0, stream>>>(X, ABuf);
    k_spmm<<<(NN + 3) / 4, 256, 0, stream>>>(X, row_ptr, csr_src, csr_wn, ABuf);
    k_prep<<<96, 256, 0, stream>>>(Wx0, Wx1, bx, bh, wc, bg, Wfrag, biasv, wc2);
    k_gemm<<<(NN + 63) / 64, 256, 0, stream>>>(ABuf, Wfrag, biasv, wc2, out);
}

// Round 2
// 535.615 us; speedup vs baseline: 1.3748x; 1.3748x over previous
//
#include <hip/hip_runtime.h>
#include <hip/hip_fp16.h>

// Problem constants (fixed by the reference)
#define NN 50000      // nodes
#define EE 800000     // edges
#define FF 64         // F_IN = F_OUT
#define PP 8          // periods
#define NPAD 50048    // padded rows (multiple of 64, >= max GEMM tile row)

typedef _Float16 half8 __attribute__((ext_vector_type(8)));
typedef float floatx4 __attribute__((ext_vector_type(4)));

static constexpr size_t al512(size_t x) { return (x + 511) & ~size_t(511); }
static constexpr size_t OFF_DEG  = 0;                                  // float[NN]
static constexpr size_t OFF_CNT  = al512(OFF_DEG  + (size_t)NN*4);     // int[NN]
static constexpr size_t OFF_DIS  = al512(OFF_CNT  + (size_t)NN*4);     // float[NN]
static constexpr size_t OFF_ROWP = al512(OFF_DIS  + (size_t)NN*4);     // int[NN+1]
static constexpr size_t OFF_CUR  = al512(OFF_ROWP + (size_t)(NN+1)*4); // int[NN]
static constexpr size_t OFF_PART = al512(OFF_CUR  + (size_t)NN*4);     // int[64]
static constexpr size_t OFF_CSRP = al512(OFF_PART + 64*4);             // int2[EE]
static constexpr size_t OFF_BIAS = al512(OFF_CSRP + (size_t)EE*8);     // float[192]
static constexpr size_t OFF_WC2  = al512(OFF_BIAS + 192*4);            // float[64]
static constexpr size_t OFF_WFRG = al512(OFF_WC2  + 64*4);             // half[24576]
static constexpr size_t OFF_XB   = al512(OFF_WFRG + (size_t)24576*2);  // half[NPAD*512]
static constexpr size_t OFF_TB   = al512(OFF_XB   + (size_t)NPAD*512*2); // half[NPAD*512]

// ---- K1: out-degree by src (float) + in-degree count by dst (int) ----------
__global__ void k_deg_cnt(const int* __restrict__ src, const int* __restrict__ dst,
                          const float* __restrict__ ew,
                          float* __restrict__ deg, int* __restrict__ cnt) {
    int e = blockIdx.x * 256 + threadIdx.x;
    if (e < EE) {
        atomicAdd(deg + src[e], ew[e]);
        atomicAdd(cnt + dst[e], 1);
    }
}

// ---- K2: dis[n] = deg>0 ? rsqrt(max(deg,1e-12)) : 0 ------------------------
__global__ void k_dis(const float* __restrict__ deg, float* __restrict__ dis) {
    int n = blockIdx.x * 256 + threadIdx.x;
    if (n < NN) {
        float d = deg[n];
        dis[n] = d > 0.f ? rsqrtf(fmaxf(d, 1e-12f)) : 0.f;
    }
}

// ---- K3a: per-block (1024-wide) inclusive scan via wave shfl ---------------
__global__ void k_scanA(const int* __restrict__ cnt, int* __restrict__ incl,
                        int* __restrict__ partial) {
    int tid = threadIdx.x;
    int i = blockIdx.x * 1024 + tid;
    int v = (i < NN) ? cnt[i] : 0;
    int lane = tid & 63, w = tid >> 6;
    int s = v;
#pragma unroll
    for (int d = 1; d < 64; d <<= 1) {
        int t = __shfl_up(s, d);
        if (lane >= d) s += t;
    }
    __shared__ int wsum[16];
    if (lane == 63) wsum[w] = s;
    __syncthreads();
    if (w == 0) {
        int x = (lane < 16) ? wsum[lane] : 0;
#pragma unroll
        for (int d = 1; d < 16; d <<= 1) {
            int t = __shfl_up(x, d);
            if (lane >= d) x += t;
        }
        if (lane < 16) wsum[lane] = x;
    }
    __syncthreads();
    int inc = s + (w > 0 ? wsum[w - 1] : 0);
    if (i < NN) incl[i] = inc;
    if (tid == 1023) partial[blockIdx.x] = inc;  // block total (tail padded w/ 0)
}

// ---- K3b: scan the 49 block partials (in place -> exclusive), total --------
__global__ void k_scanB(int* __restrict__ partial, int* __restrict__ row_ptr, int nblk) {
    if (threadIdx.x == 0) {
        int run = 0;
        for (int b = 0; b < nblk; ++b) { int t = partial[b]; partial[b] = run; run += t; }
        row_ptr[NN] = run;
    }
}

// ---- K3c: add offsets -> exclusive row_ptr + cursor ------------------------
__global__ void k_scanC(const int* __restrict__ incl, const int* __restrict__ cnt,
                        const int* __restrict__ partial,
                        int* __restrict__ row_ptr, int* __restrict__ cursor) {
    int i = blockIdx.x * 1024 + threadIdx.x;
    if (i < NN) {
        int excl = partial[blockIdx.x] + incl[i] - cnt[i];
        row_ptr[i] = excl;
        cursor[i] = excl;
    }
}

// ---- K4: scatter edges into CSR buckets by dst (packed 8B) -----------------
__global__ void k_scatter(const int* __restrict__ src, const int* __restrict__ dst,
                          const float* __restrict__ ew, const float* __restrict__ dis,
                          int* __restrict__ cursor, int2* __restrict__ csr) {
    int e = blockIdx.x * 256 + threadIdx.x;
    if (e < EE) {
        int s = src[e], d = dst[e];
        float wn = -dis[s] * ew[e] * dis[d];
        int pos = atomicAdd(cursor + d, 1);
        int2 pr; pr.x = s; pr.y = __float_as_int(wn);
        csr[pos] = pr;
    }
}

// ---- K5: transpose+cvt X (N,64,8) f32 -> XBuf[n][p][f] f16 -----------------
// wave per node; LDS tile per wave; coalesced 16B loads and stores.
__global__ void k_xpose(const float* __restrict__ X, _Float16* __restrict__ XB) {
    __shared__ _Float16 tile[4][512];
    int wid = threadIdx.x >> 6, lane = threadIdx.x & 63;
    int n = blockIdx.x * 4 + wid;
    if (n < NN) {
        const float4* xp = (const float4*)(X + (size_t)n * 512 + lane * 8);
        float4 a = xp[0], b = xp[1];
        float v[8] = {a.x, a.y, a.z, a.w, b.x, b.y, b.z, b.w};
#pragma unroll
        for (int p = 0; p < PP; ++p)               // [p][f] layout, f = lane
            tile[wid][p * 64 + lane] = (_Float16)v[p];
    }
    __syncthreads();
    if (n < NN) {
        half8 v = *(const half8*)&tile[wid][lane * 8];
        *(half8*)(XB + (size_t)n * 512 + lane * 8) = v;
    }
}

// ---- K6: SpMM gather: TB[n][p][f] = sum_e wn * XB[src][p][f] ---------------
__global__ void k_spmm(const _Float16* __restrict__ XB, const int* __restrict__ row_ptr,
                       const int2* __restrict__ csr, _Float16* __restrict__ TB) {
    int wid = threadIdx.x >> 6, lane = threadIdx.x & 63;
    int n = blockIdx.x * 4 + wid;
    if (n >= NN) return;
    float acc[8] = {0.f, 0.f, 0.f, 0.f, 0.f, 0.f, 0.f, 0.f};
    int beg = row_ptr[n], end = row_ptr[n + 1];
    int k = beg;
    for (; k + 1 < end; k += 2) {
        int2 e0 = csr[k], e1 = csr[k + 1];
        half8 a = *((const half8*)(XB + (size_t)e0.x * 512) + lane);
        half8 b = *((const half8*)(XB + (size_t)e1.x * 512) + lane);
        float w0 = __int_as_float(e0.y), w1 = __int_as_float(e1.y);
#pragma unroll
        for (int j = 0; j < 8; ++j) acc[j] += w0 * (float)a[j];
#pragma unroll
        for (int j = 0; j < 8; ++j) acc[j] += w1 * (float)b[j];
    }
    if (k < end) {
        int2 e0 = csr[k];
        half8 a = *((const half8*)(XB + (size_t)e0.x * 512) + lane);
        float w0 = __int_as_float(e0.y);
#pragma unroll
        for (int j = 0; j < 8; ++j) acc[j] += w0 * (float)a[j];
    }
    half8 st;
#pragma unroll
    for (int j = 0; j < 8; ++j) st[j] = (_Float16)acc[j];
    *(half8*)(TB + (size_t)n * 512 + lane * 8) = st;
}

// ---- K7: weight prep: pack W into MFMA B-fragment layout + biases ----------
// Wfrag[((ks*12+ct)*64 + lane)*8 + j] = W[k = ks*32 + (lane>>4)*8 + j][c = ct*16 + (lane&15)]
// where W[k][g'*64+j64] = (k<64 ? Wx0 : Wx1)[gmap[g']][k%64][j64]
__global__ void k_prep(const float* __restrict__ Wx0, const float* __restrict__ Wx1,
                       const float* __restrict__ bx, const float* __restrict__ bh,
                       const float* __restrict__ wc, const float* __restrict__ bg,
                       _Float16* __restrict__ Wfrag, float* __restrict__ biasv,
                       float* __restrict__ wc2) {
    int t = blockIdx.x * 256 + threadIdx.x;
    const int gmap[3] = {0, 2, 3};
    if (t < 24576) {
        int j8 = t & 7;
        int lane = (t >> 3) & 63;
        int rem = t >> 9;           // [0,48)
        int ct = rem % 12;
        int ks = rem / 12;
        int k = ks * 32 + (lane >> 4) * 8 + j8;
        int gp = ct >> 2;
        int g = gmap[gp];
        int j64 = (ct & 3) * 16 + (lane & 15);
        float val = (k < 64) ? Wx0[((size_t)g * 64 + k) * 64 + j64]
                             : Wx1[((size_t)g * 64 + (k - 64)) * 64 + j64];
        Wfrag[t] = (_Float16)val;
    }
    if (t < 192) {
        int gp = t / 64, j = t % 64;
        int g = gmap[gp];
        biasv[t] = bx[g * 64 + j] + bh[g * 64 + j] + bg[g * 64 + j];
    }
    if (t < 64) wc2[t] = wc[2 * 64 + t];
}

__device__ __forceinline__ float sigmoidf_fast(float x) {
    return 1.f / (1.f + __expf(-x));
}
__device__ __forceinline__ float tanhf_fast(float x) {
    float e2 = __expf(2.f * x);
    return 1.f - 2.f / (e2 + 1.f);
}

// ---- K8: MFMA GEMM (N x 128) @ (128 x 192) per period + fused LSTM epilogue
// Block = 256 thr = 4 waves; wave handles 16 nodes x 192 cols (12 MFMA tiles).
// A-fragments come straight from XB (k<64) and TB (k>=64): 16B loads.
__global__ __launch_bounds__(256) void k_gemm(const _Float16* __restrict__ XB,
                                              const _Float16* __restrict__ TB,
                                              const _Float16* __restrict__ Wfrag,
                                              const float* __restrict__ biasv,
                                              const float* __restrict__ wc2,
                                              float* __restrict__ out) {
    int wid = threadIdx.x >> 6, lane = threadIdx.x & 63;
    int n0 = blockIdx.x * 64 + wid * 16;
    int jj = lane & 15, quad = lane >> 4;

    float bi[4], bc[4], bo[4], wcv[4];
#pragma unroll
    for (int c4 = 0; c4 < 4; ++c4) {
        int j = c4 * 16 + jj;
        bi[c4] = biasv[j];
        bc[c4] = biasv[64 + j];
        bo[c4] = biasv[128 + j];
        wcv[c4] = wc2[j];
    }

    const half8* Wf = (const half8*)Wfrag;
    floatx4 outacc[4];
#pragma unroll
    for (int c4 = 0; c4 < 4; ++c4) outacc[c4] = (floatx4){0.f, 0.f, 0.f, 0.f};

    int arow = n0 + jj;  // A-fragment: m = lane&15

#pragma unroll 1
    for (int p = 0; p < PP; ++p) {
        const half8* Ax = (const half8*)(XB + (size_t)arow * 512 + p * 64);
        const half8* At = (const half8*)(TB + (size_t)arow * 512 + p * 64);
        half8 af[4];
        af[0] = Ax[quad];      // k = quad*8 + j
        af[1] = Ax[4 + quad];  // k = 32 + quad*8 + j
        af[2] = At[quad];      // k = 64 + ...
        af[3] = At[4 + quad];  // k = 96 + ...
        floatx4 acc[12];
#pragma unroll
        for (int t = 0; t < 12; ++t) acc[t] = (floatx4){0.f, 0.f, 0.f, 0.f};
#pragma unroll
        for (int ks = 0; ks < 4; ++ks) {
#pragma unroll
            for (int ct = 0; ct < 12; ++ct) {
                half8 bf = Wf[(ks * 12 + ct) * 64 + lane];
                acc[ct] = __builtin_amdgcn_mfma_f32_16x16x32_f16(af[ks], bf, acc[ct], 0, 0, 0);
            }
        }
        // fused epilogue: I=sig(ai); T=tanh(ac); Cn=I*T; O=sig(ao+wc2*Cn); out+=O*tanh(Cn)
#pragma unroll
        for (int c4 = 0; c4 < 4; ++c4) {
#pragma unroll
            for (int r = 0; r < 4; ++r) {
                float ai = acc[c4][r] + bi[c4];
                float ac = acc[4 + c4][r] + bc[c4];
                float ao = acc[8 + c4][r] + bo[c4];
                float I = sigmoidf_fast(ai);
                float T = tanhf_fast(ac);
                float Cn = I * T;
                float O = sigmoidf_fast(ao + wcv[c4] * Cn);
                outacc[c4][r] += O * tanhf_fast(Cn);
            }
        }
    }
    // store: row n = n0 + quad*4 + r, col = c4*16 + jj
#pragma unroll
    for (int c4 = 0; c4 < 4; ++c4) {
#pragma unroll
        for (int r = 0; r < 4; ++r) {
            int n = n0 + quad * 4 + r;
            if (n < NN) out[(size_t)n * 64 + c4 * 16 + jj] = outacc[c4][r];
        }
    }
}

extern "C" void kernel_launch(void* const* d_in, const int* in_sizes, int n_in,
                              void* d_out, int out_size, void* d_ws, size_t ws_size,
                              hipStream_t stream) {
    const float* X   = (const float*)d_in[0];
    const int*   ei  = (const int*)d_in[1];
    const float* ew  = (const float*)d_in[2];
    const float* Wx0 = (const float*)d_in[3];
    const float* Wx1 = (const float*)d_in[4];
    const float* bx  = (const float*)d_in[5];
    // d_in[6], d_in[7] (Wh0, Wh1) are dead: H=0
    const float* bh  = (const float*)d_in[8];
    const float* wc  = (const float*)d_in[9];
    const float* bg  = (const float*)d_in[10];
    float* out = (float*)d_out;

    const int* src = ei;
    const int* dst = ei + EE;

    char* ws = (char*)d_ws;
    float* deg     = (float*)(ws + OFF_DEG);
    int*   cnt     = (int*)(ws + OFF_CNT);
    float* dis     = (float*)(ws + OFF_DIS);
    int*   row_ptr = (int*)(ws + OFF_ROWP);
    int*   cursor  = (int*)(ws + OFF_CUR);
    int*   partial = (int*)(ws + OFF_PART);
    int2*  csr     = (int2*)(ws + OFF_CSRP);
    float* biasv   = (float*)(ws + OFF_BIAS);
    float* wc2     = (float*)(ws + OFF_WC2);
    _Float16* Wfrag = (_Float16*)(ws + OFF_WFRG);
    _Float16* XB    = (_Float16*)(ws + OFF_XB);
    _Float16* TB    = (_Float16*)(ws + OFF_TB);

    // zero deg + cnt (contiguous region at front of ws)
    hipMemsetAsync(ws, 0, OFF_CNT + (size_t)NN * 4, stream);

    const int NSCAN = (NN + 1023) / 1024;  // 49
    k_deg_cnt<<<(EE + 255) / 256, 256, 0, stream>>>(src, dst, ew, deg, cnt);
    k_dis<<<(NN + 255) / 256, 256, 0, stream>>>(deg, dis);
    k_scanA<<<NSCAN, 1024, 0, stream>>>(cnt, cursor, partial);  // cursor <- inclusive scan
    k_scanB<<<1, 64, 0, stream>>>(partial, row_ptr, NSCAN);
    k_scanC<<<NSCAN, 1024, 0, stream>>>(cursor, cnt, partial, row_ptr, cursor);
    k_scatter<<<(EE + 255) / 256, 256, 0, stream>>>(src, dst, ew, dis, cursor, csr);
    k_xpose<<<(NN + 3) / 4, 256, 0, stream>>>(X, XB);
    k_spmm<<<(NN + 3) / 4, 256, 0, stream>>>(XB, row_ptr, csr, TB);
    k_prep<<<96, 256, 0, stream>>>(Wx0, Wx1, bx, bh, wc, bg, Wfrag, biasv, wc2);
    k_gemm<<<(NN + 63) / 64, 256, 0, stream>>>(XB, TB, Wfrag, biasv, wc2, out);
}